// Round 1
// baseline (754.502 us; speedup 1.0000x reference)
//
#include <hip/hip_runtime.h>
#include <type_traits>
#include <utility>
#include <stdint.h>
#include <stddef.h>

#define TOKENS 8192
#define CDIM 2048
#define FDIM 8192
#define EPSV 1.1920929e-07f

typedef __attribute__((ext_vector_type(8))) short short8;
typedef __attribute__((ext_vector_type(8))) __bf16 bf16x8;
typedef __attribute__((ext_vector_type(4))) float floatx4;

// Detect which operand typing this clang uses for the gfx950 bf16 MFMA builtin.
template <typename V, typename = void> struct CanMfma : std::false_type {};
template <typename V>
struct CanMfma<V, std::void_t<decltype(__builtin_amdgcn_mfma_f32_16x16x32_bf16(
    std::declval<V>(), std::declval<V>(), std::declval<floatx4>(), 0, 0, 0))>>
    : std::true_type {};
using frag_t = std::conditional_t<CanMfma<short8>::value, short8, bf16x8>;

__device__ __forceinline__ floatx4 mfma_bf16(frag_t a, frag_t b, floatx4 c) {
    return __builtin_amdgcn_mfma_f32_16x16x32_bf16(a, b, c, 0, 0, 0);
}

// round-to-nearest-even f32 -> bf16
__device__ __forceinline__ unsigned short f2bf(float f) {
    unsigned int u = __float_as_uint(f);
    u += 0x7fffu + ((u >> 16) & 1u);
    return (unsigned short)(u >> 16);
}

__global__ void zero_kernel(int* p) { if (threadIdx.x == 0) *p = 0; }

// Convert both weight matrices fp32 -> bf16 in one launch.
__global__ __launch_bounds__(256) void cvt2_kernel(
    const float* __restrict__ s1, unsigned short* __restrict__ d1, int n1,
    const float* __restrict__ s2, unsigned short* __restrict__ d2, int n2)
{
    int i = blockIdx.x * 256 + threadIdx.x;
    const float4* s; ushort4* d;
    if (i < n1) { s = (const float4*)s1; d = (ushort4*)d1; }
    else if (i < n1 + n2) { s = (const float4*)s2; d = (ushort4*)d2; i -= n1; }
    else return;
    float4 v = s[i];
    ushort4 o;
    o.x = f2bf(v.x); o.y = f2bf(v.y); o.z = f2bf(v.z); o.w = f2bf(v.w);
    d[i] = o;
}

// Per token: router logit, sigmoid mask, RMSNorm; compact selected tokens into
// Xn (bf16). ALL tokens get out = x (residual base); GEMM2 atomic-adds the
// gated MLP on top for selected tokens.
__global__ __launch_bounds__(256) void router_kernel(
    const float* __restrict__ x, const float* __restrict__ wr,
    float* __restrict__ out, unsigned short* __restrict__ Xn,
    int* __restrict__ idx, float* __restrict__ mv, int* __restrict__ cnt)
{
    const int token = blockIdx.x;
    const int tid = threadIdx.x;
    const float4* xr = (const float4*)(x + (size_t)token * CDIM);
    const float4* w4 = (const float4*)wr;
    float4 a0 = xr[tid];
    float4 a1 = xr[tid + 256];
    float4 b0 = w4[tid];
    float4 b1 = w4[tid + 256];
    float ss = a0.x*a0.x + a0.y*a0.y + a0.z*a0.z + a0.w*a0.w
             + a1.x*a1.x + a1.y*a1.y + a1.z*a1.z + a1.w*a1.w;
    float dt = a0.x*b0.x + a0.y*b0.y + a0.z*b0.z + a0.w*b0.w
             + a1.x*b1.x + a1.y*b1.y + a1.z*b1.z + a1.w*b1.w;
    #pragma unroll
    for (int off = 32; off > 0; off >>= 1) {
        ss += __shfl_down(ss, off);
        dt += __shfl_down(dt, off);
    }
    __shared__ float red_ss[4], red_dt[4];
    __shared__ float s_rms;
    __shared__ int s_pos;
    const int wave = tid >> 6;
    if ((tid & 63) == 0) { red_ss[wave] = ss; red_dt[wave] = dt; }
    __syncthreads();
    if (tid == 0) {
        float S = red_ss[0] + red_ss[1] + red_ss[2] + red_ss[3];
        float D = red_dt[0] + red_dt[1] + red_dt[2] + red_dt[3];
        float prob = 1.0f / (1.0f + expf(-D));
        s_rms = 1.0f / sqrtf(S * (1.0f / (float)CDIM) + EPSV);
        int pos = -1;
        if (prob > 0.5f) {
            pos = atomicAdd(cnt, 1);
            idx[pos] = token;
            mv[pos] = (1.0f + prob) - prob;  // replicate STE mask_i rounding exactly
        }
        s_pos = pos;
    }
    __syncthreads();
    // residual base for ALL tokens
    float4* op = (float4*)(out + (size_t)token * CDIM);
    op[tid] = a0;
    op[tid + 256] = a1;
    const float rms = s_rms;
    const int pos = s_pos;
    if (pos >= 0) {
        ushort4* xp = (ushort4*)(Xn + (size_t)pos * CDIM);
        ushort4 o;
        o.x = f2bf(a0.x * rms); o.y = f2bf(a0.y * rms); o.z = f2bf(a0.z * rms); o.w = f2bf(a0.w * rms);
        xp[tid] = o;
        o.x = f2bf(a1.x * rms); o.y = f2bf(a1.y * rms); o.z = f2bf(a1.z * rms); o.w = f2bf(a1.w * rms);
        xp[tid + 256] = o;
    }
}

// C[m][n] = sum_k A[m][k]*B[n][k], A:[M][K] bf16 (compacted rows), B:[N][K] bf16.
// 128x128 tile, BK=64, 4 waves 2x2, 4x4 MFMA 16x16x32; global_load_lds(16B)
// staging with XOR swizzle on the GLOBAL address side.
//
// DOUBLE-BUFFERED LDS (T3-minimum 2-phase): stage tile kt+1 into buf^1 while
// computing tile kt from buf; ONE __syncthreads() per iteration. Its implicit
// vmcnt(0)+lgkmcnt(0) drain gives both (a) prefetch completion before the next
// compute and (b) the WAR fence: a wave can only reach iteration kt's stage of
// buf[(kt+1)&1] after ALL waves passed the kt-1 barrier, i.e. after their
// lgkm-drained ds_reads of that same buffer. Removes the per-iteration
// serialized (load-latency + compute) -> max(latency, compute).
//
// 8x8 SUPERTILE raster with XCD-RECT remap: launch_idx%8 ~ XCD, so within a
// supertile each XCD's 8 blocks form a 4m x 2n RECTANGLE (was 1x8 row).
// Per-XCD L2 set: 4 A-panels + 2 B-panels ~ 3 MB <= 4 MB L2 (was 4.5 MB ->
// B evicted between supertiles). B-panel XCD duplication 8 -> 2.
// KSPLIT: blockIdx.z takes K-chunk [z*K/KSPLIT, ...); MODE 2 atomic-adds.
// MODE 1: Hout[m][n] = bf16(relu(acc)^2).  MODE 2: atomicAdd scale*acc to out.
template <int K, int MODE, int LDO, int KSPLIT>
__global__ __launch_bounds__(256) void gemm_bt(
    const unsigned short* __restrict__ A,
    const unsigned short* __restrict__ B,
    unsigned short* __restrict__ Hout,
    float* __restrict__ out,
    const int* __restrict__ idx,
    const float* __restrict__ mv,
    const int* __restrict__ cntp)
{
    const int cnt = *cntp;
    // supertile swizzle (gridDim.x == 64 m-panels for both GEMMs)
    const int bid = blockIdx.y * 64 + blockIdx.x;
    const int s = bid >> 6;          // supertile id
    const int w = bid & 63;          // position within 8x8 supertile
    const int r = w & 7;             // ~XCD id (hw round-robins launch idx % 8)
    const int t = w >> 3;            // position within this XCD's rect
    // 4m x 2n rect per XCD
    const int mi = (s & 7) * 8 + (r >> 2) * 4 + (t & 3);
    const int ni = (s >> 3) * 8 + (r & 3) * 2 + (t >> 2);
    const int m0 = mi * 128;
    if (m0 >= cnt) return;
    const int n0 = ni * 128;
    const int k0 = (int)blockIdx.z * (K / KSPLIT);   // element offset in k

    __shared__ alignas(16) unsigned short lA[2][128 * 64];
    __shared__ alignas(16) unsigned short lB[2][128 * 64];

    const int tid = threadIdx.x;
    const int wave = tid >> 6;
    const int lane = tid & 63;
    const int wm = (wave >> 1) * 64;
    const int wn = (wave & 1) * 64;
    const int quad = lane >> 4;
    const int l16 = lane & 15;

    // staging: wave w, issue p covers rows p*32+w*8 .. +8; lane i -> row +i/8,
    // global 16B chunk (i&7)^(i/8) (swizzle), LDS chunk i&7 (hardware lane order)
    const int srow = lane >> 3;
    const int schunk = (lane & 7) ^ srow;

    const unsigned short* ap[4];
    const unsigned short* bp[4];
    #pragma unroll
    for (int p = 0; p < 4; ++p) {
        const int rr = p * 32 + wave * 8 + srow;
        ap[p] = A + (size_t)(m0 + rr) * K + k0 + schunk * 8;
        bp[p] = B + (size_t)(n0 + rr) * K + k0 + schunk * 8;
    }

    auto stage = [&](int buf) {
        #pragma unroll
        for (int p = 0; p < 4; ++p) {
            __builtin_amdgcn_global_load_lds(
                (__attribute__((address_space(1))) void*)ap[p],
                (__attribute__((address_space(3))) void*)&lA[buf][(p * 32 + wave * 8) * 64],
                16, 0, 0);
            __builtin_amdgcn_global_load_lds(
                (__attribute__((address_space(1))) void*)bp[p],
                (__attribute__((address_space(3))) void*)&lB[buf][(p * 32 + wave * 8) * 64],
                16, 0, 0);
            ap[p] += 64;
            bp[p] += 64;
        }
    };

    floatx4 acc[4][4] = {};

    const int NT = K / (64 * KSPLIT);
    int cur = 0;
    stage(0);
    __syncthreads();  // drains vmcnt(0): tile 0 landed

    for (int kt = 0; kt < NT; ++kt) {
        if (kt + 1 < NT) stage(cur ^ 1);   // prefetch overlaps compute below
        #pragma unroll
        for (int st = 0; st < 2; ++st) {
            frag_t af[4], bfv[4];
            #pragma unroll
            for (int tt = 0; tt < 4; ++tt) {
                const int ra = wm + tt * 16 + l16;
                const int ca = ((st * 4 + quad) ^ (ra & 7)) * 8;
                af[tt] = *(const frag_t*)&lA[cur][ra * 64 + ca];
                const int rb = wn + tt * 16 + l16;
                const int cb = ((st * 4 + quad) ^ (rb & 7)) * 8;
                bfv[tt] = *(const frag_t*)&lB[cur][rb * 64 + cb];
            }
            #pragma unroll
            for (int tm = 0; tm < 4; ++tm)
                #pragma unroll
                for (int tn = 0; tn < 4; ++tn)
                    acc[tm][tn] = mfma_bf16(af[tm], bfv[tn], acc[tm][tn]);
        }
        __syncthreads();  // drains vmcnt(0) (prefetch done) + lgkmcnt (WAR fence)
        cur ^= 1;
    }

    // C/D layout (verified m89/m91): col(n) = lane&15, row(m) = quad*4 + reg
    if (MODE == 1) {
        #pragma unroll
        for (int tm = 0; tm < 4; ++tm) {
            const int gm = m0 + wm + tm * 16 + quad * 4;
            #pragma unroll
            for (int tn = 0; tn < 4; ++tn) {
                const int gn = n0 + wn + tn * 16 + l16;
                #pragma unroll
                for (int v = 0; v < 4; ++v) {
                    float h = fmaxf(acc[tm][tn][v], 0.0f);  // fmax eats NaN pad rows too
                    Hout[(size_t)(gm + v) * LDO + gn] = f2bf(h * h);
                }
            }
        }
    } else {
        #pragma unroll
        for (int tm = 0; tm < 4; ++tm) {
            const int gmb = m0 + wm + tm * 16 + quad * 4;
            #pragma unroll
            for (int v = 0; v < 4; ++v) {
                const int gm = gmb + v;
                if (gm < cnt) {  // never read poisoned idx/mv beyond cnt
                    const int token = idx[gm];
                    const float scale = mv[gm];
                    #pragma unroll
                    for (int tn = 0; tn < 4; ++tn) {
                        const int gn = n0 + wn + tn * 16 + l16;
                        atomicAdd(&out[(size_t)token * LDO + gn], scale * acc[tm][tn][v]);
                    }
                }
            }
        }
    }
}

extern "C" void kernel_launch(void* const* d_in, const int* in_sizes, int n_in,
                              void* d_out, int out_size, void* d_ws, size_t ws_size,
                              hipStream_t stream)
{
    const float* x   = (const float*)d_in[0];
    const float* wfc = (const float*)d_in[1];
    const float* wpr = (const float*)d_in[2];
    const float* wrt = (const float*)d_in[3];
    float* out = (float*)d_out;

    // ws layout (bytes): [cnt 256][idx 32K][mv 32K][Xn 32M][Wfc 32M][Wpr 32M][H 128M]
    char* ws = (char*)d_ws;
    int*   cnt = (int*)ws;
    int*   idx = (int*)(ws + 256);
    float* mv  = (float*)(ws + 256 + 32768);
    unsigned short* Xn  = (unsigned short*)(ws + 65792);
    unsigned short* Wfc = (unsigned short*)(ws + 65792 + 33554432ULL);
    unsigned short* Wpr = (unsigned short*)(ws + 65792 + 67108864ULL);
    unsigned short* H   = (unsigned short*)(ws + 65792 + 100663296ULL);

    const int n4 = FDIM * CDIM / 4;  // float4 count per weight matrix
    zero_kernel<<<1, 64, 0, stream>>>(cnt);
    cvt2_kernel<<<(2 * n4 + 255) / 256, 256, 0, stream>>>(wfc, Wfc, n4, wpr, Wpr, n4);
    router_kernel<<<TOKENS, 256, 0, stream>>>(x, wrt, out, Xn, idx, mv, cnt);
    // GEMM1: H[m][f] = relu(Xn @ Wfc^T)^2, M=cnt (<=8192), N=8192, K=2048
    gemm_bt<CDIM, 1, FDIM, 1><<<dim3(64, FDIM / 128), 256, 0, stream>>>(
        Xn, Wfc, H, nullptr, nullptr, nullptr, cnt);
    // GEMM2: out[token][c] += mask_i * (H @ Wpr^T), M=cnt, N=2048, K=8192, split-K x2
    gemm_bt<FDIM, 2, CDIM, 2><<<dim3(64, CDIM / 128, 2), 256, 0, stream>>>(
        H, Wpr, nullptr, out, idx, mv, cnt);
}

// Round 2
// 716.166 us; speedup vs baseline: 1.0535x; 1.0535x over previous
//
#include <hip/hip_runtime.h>
#include <type_traits>
#include <utility>
#include <stdint.h>
#include <stddef.h>

#define TOKENS 8192
#define CDIM 2048
#define FDIM 8192
#define EPSV 1.1920929e-07f

typedef __attribute__((ext_vector_type(8))) short short8;
typedef __attribute__((ext_vector_type(8))) __bf16 bf16x8;
typedef __attribute__((ext_vector_type(4))) float floatx4;

// Detect which operand typing this clang uses for the gfx950 bf16 MFMA builtin.
template <typename V, typename = void> struct CanMfma : std::false_type {};
template <typename V>
struct CanMfma<V, std::void_t<decltype(__builtin_amdgcn_mfma_f32_16x16x32_bf16(
    std::declval<V>(), std::declval<V>(), std::declval<floatx4>(), 0, 0, 0))>>
    : std::true_type {};
using frag_t = std::conditional_t<CanMfma<short8>::value, short8, bf16x8>;

__device__ __forceinline__ floatx4 mfma_bf16(frag_t a, frag_t b, floatx4 c) {
    return __builtin_amdgcn_mfma_f32_16x16x32_bf16(a, b, c, 0, 0, 0);
}

// round-to-nearest-even f32 -> bf16
__device__ __forceinline__ unsigned short f2bf(float f) {
    unsigned int u = __float_as_uint(f);
    u += 0x7fffu + ((u >> 16) & 1u);
    return (unsigned short)(u >> 16);
}

__global__ void zero_kernel(int* p) { if (threadIdx.x == 0) *p = 0; }

// Convert both weight matrices fp32 -> bf16 in one launch.
__global__ __launch_bounds__(256) void cvt2_kernel(
    const float* __restrict__ s1, unsigned short* __restrict__ d1, int n1,
    const float* __restrict__ s2, unsigned short* __restrict__ d2, int n2)
{
    int i = blockIdx.x * 256 + threadIdx.x;
    const float4* s; ushort4* d;
    if (i < n1) { s = (const float4*)s1; d = (ushort4*)d1; }
    else if (i < n1 + n2) { s = (const float4*)s2; d = (ushort4*)d2; i -= n1; }
    else return;
    float4 v = s[i];
    ushort4 o;
    o.x = f2bf(v.x); o.y = f2bf(v.y); o.z = f2bf(v.z); o.w = f2bf(v.w);
    d[i] = o;
}

// Per token: router logit, sigmoid mask, RMSNorm; compact selected tokens into
// Xn (bf16). ALL tokens get out = x (residual base); GEMM2 atomic-adds the
// gated MLP on top for selected tokens.
__global__ __launch_bounds__(256) void router_kernel(
    const float* __restrict__ x, const float* __restrict__ wr,
    float* __restrict__ out, unsigned short* __restrict__ Xn,
    int* __restrict__ idx, float* __restrict__ mv, int* __restrict__ cnt)
{
    const int token = blockIdx.x;
    const int tid = threadIdx.x;
    const float4* xr = (const float4*)(x + (size_t)token * CDIM);
    const float4* w4 = (const float4*)wr;
    float4 a0 = xr[tid];
    float4 a1 = xr[tid + 256];
    float4 b0 = w4[tid];
    float4 b1 = w4[tid + 256];
    float ss = a0.x*a0.x + a0.y*a0.y + a0.z*a0.z + a0.w*a0.w
             + a1.x*a1.x + a1.y*a1.y + a1.z*a1.z + a1.w*a1.w;
    float dt = a0.x*b0.x + a0.y*b0.y + a0.z*b0.z + a0.w*b0.w
             + a1.x*b1.x + a1.y*b1.y + a1.z*b1.z + a1.w*b1.w;
    #pragma unroll
    for (int off = 32; off > 0; off >>= 1) {
        ss += __shfl_down(ss, off);
        dt += __shfl_down(dt, off);
    }
    __shared__ float red_ss[4], red_dt[4];
    __shared__ float s_rms;
    __shared__ int s_pos;
    const int wave = tid >> 6;
    if ((tid & 63) == 0) { red_ss[wave] = ss; red_dt[wave] = dt; }
    __syncthreads();
    if (tid == 0) {
        float S = red_ss[0] + red_ss[1] + red_ss[2] + red_ss[3];
        float D = red_dt[0] + red_dt[1] + red_dt[2] + red_dt[3];
        float prob = 1.0f / (1.0f + expf(-D));
        s_rms = 1.0f / sqrtf(S * (1.0f / (float)CDIM) + EPSV);
        int pos = -1;
        if (prob > 0.5f) {
            pos = atomicAdd(cnt, 1);
            idx[pos] = token;
            mv[pos] = (1.0f + prob) - prob;  // replicate STE mask_i rounding exactly
        }
        s_pos = pos;
    }
    __syncthreads();
    // residual base for ALL tokens
    float4* op = (float4*)(out + (size_t)token * CDIM);
    op[tid] = a0;
    op[tid + 256] = a1;
    const float rms = s_rms;
    const int pos = s_pos;
    if (pos >= 0) {
        ushort4* xp = (ushort4*)(Xn + (size_t)pos * CDIM);
        ushort4 o;
        o.x = f2bf(a0.x * rms); o.y = f2bf(a0.y * rms); o.z = f2bf(a0.z * rms); o.w = f2bf(a0.w * rms);
        xp[tid] = o;
        o.x = f2bf(a1.x * rms); o.y = f2bf(a1.y * rms); o.z = f2bf(a1.z * rms); o.w = f2bf(a1.w * rms);
        xp[tid + 256] = o;
    }
}

// C[m][n] = sum_k A[m][k]*B[n][k], A:[M][K] bf16 (compacted rows), B:[N][K] bf16.
//
// 256x256 tile, BK=32, 512 threads = 8 waves (2M x 4N), per-wave 128x64 output,
// acc[8][4] 16x16x32 MFMA fragments.
//
// COUNTED-VMCNT RING PIPELINE (T3+T4, race-free variant): LDS is a ring of 4
// K-tile slots (A 16KB + B 16KB each = 128KB dynamic LDS). Iteration u:
//   stage(u+3) -> slot[(u+3)&3]        (4 global_load_lds / thread)
//   s_waitcnt vmcnt(12)                (3 tiles in flight; NEVER drains to 0)
//   s_barrier                          (publish: tile u landed for all waves)
//   12 ds_read_b128 -> 32 MFMA (setprio(1) around cluster, T5)
//   s_barrier                          (slot[(u-1)&3]'s reads done -> reusable)
// stage(u+3) overwrites slot[(u-1)&3], whose last ds_read completed before the
// PREVIOUS iteration's end barrier -> no latency assumptions, provably safe.
// Loads get 3 iterations (~1200cy) to land vs ~900cy HBM latency.
//
// LDS layout (per slot, A then B at +8192 u16): logical (row, k-chunk q of 8
// bf16) stored at u16 offset row*32 + (q ^ ((row>>1)&3))*8. ds_read_b128 of a
// fragment column then hits 8 distinct 16B slots per 16-lane group (2-way
// bank aliasing = free, same structure that measures 0 conflicts today).
// global_load_lds writes LDS linearly; the XOR is applied on the GLOBAL source
// address (rule: swizzle both sides or neither).
//
// 8x8 SUPERTILE raster (round-0 scheme, measured-better): m-fastest within
// supertile; MP=32 m-panels -> 4 supertile rows.
// KSPLIT: blockIdx.z takes K-chunk; MODE 2 atomic-adds.
// MODE 1: Hout[m][n] = bf16(relu(acc)^2).  MODE 2: atomicAdd scale*acc to out.
template <int K, int MODE, int LDO, int KSPLIT>
__global__ __launch_bounds__(512, 2) void gemm_bt(
    const unsigned short* __restrict__ A,
    const unsigned short* __restrict__ B,
    unsigned short* __restrict__ Hout,
    float* __restrict__ out,
    const int* __restrict__ idx,
    const float* __restrict__ mv,
    const int* __restrict__ cntp)
{
    const int cnt = *cntp;
    // supertile swizzle: gridDim.x == 32 m-panels
    const int bid = blockIdx.y * 32 + blockIdx.x;
    const int s = bid >> 6;          // supertile id
    const int w = bid & 63;          // position within 8x8 supertile
    const int mi = (s & 3) * 8 + (w & 7);    // m-fastest (XCD round-robin on m)
    const int ni = (s >> 2) * 8 + (w >> 3);
    const int m0 = mi * 256;
    if (m0 >= cnt) return;
    const int n0 = ni * 256;
    const int k0 = (int)blockIdx.z * (K / KSPLIT);   // element offset in k

    extern __shared__ unsigned short lds[];  // 4 slots x 16384 u16 = 128 KB

    const int tid = threadIdx.x;
    const int wave = tid >> 6;
    const int lane = tid & 63;
    const int wm = (wave >> 2) * 128;        // 2 wave-rows (M)
    const int wn = (wave & 3) * 64;          // 4 wave-cols (N)
    const int quad = lane >> 4;
    const int l16 = lane & 15;

    // staging source mapping: 16B chunk si = p*512 + tid covers
    //   row = p*128 + 2*(tid>>3) + ((tid>>2)&1),  q = (tid&3) ^ ((tid>>3)&3)
    // (derived from linear LDS order si*16B == row*64B + (q^((row>>1)&3))*16B)
    const int srow = 2 * (tid >> 3) + ((tid >> 2) & 1);
    const int sq   = (tid & 3) ^ ((tid >> 3) & 3);

    const unsigned short* ap[2];
    const unsigned short* bp[2];
    #pragma unroll
    for (int p = 0; p < 2; ++p) {
        const int r = p * 128 + srow;
        ap[p] = A + (size_t)(m0 + r) * K + k0 + sq * 8;
        bp[p] = B + (size_t)(n0 + r) * K + k0 + sq * 8;
    }

    auto stage = [&](int v) {
        unsigned short* base = &lds[(v & 3) * 16384];
        #pragma unroll
        for (int p = 0; p < 2; ++p) {
            __builtin_amdgcn_global_load_lds(
                (__attribute__((address_space(1))) void*)ap[p],
                (__attribute__((address_space(3))) void*)&base[(p * 512 + wave * 64) * 8],
                16, 0, 0);
            ap[p] += 32;
        }
        #pragma unroll
        for (int p = 0; p < 2; ++p) {
            __builtin_amdgcn_global_load_lds(
                (__attribute__((address_space(1))) void*)bp[p],
                (__attribute__((address_space(3))) void*)&base[8192 + (p * 512 + wave * 64) * 8],
                16, 0, 0);
            bp[p] += 32;
        }
    };

    floatx4 acc[8][4] = {};

    const int NT = K / (32 * KSPLIT);
    stage(0); stage(1); stage(2);   // fill pipeline: 3 tiles in flight

    for (int u = 0; u < NT; ++u) {
        const int rem = NT - 1 - u;
        if (rem >= 3) {
            stage(u + 3);
            asm volatile("s_waitcnt vmcnt(12)" ::: "memory");
        } else if (rem == 2) {
            asm volatile("s_waitcnt vmcnt(8)" ::: "memory");
        } else if (rem == 1) {
            asm volatile("s_waitcnt vmcnt(4)" ::: "memory");
        } else {
            asm volatile("s_waitcnt vmcnt(0)" ::: "memory");
        }
        __builtin_amdgcn_sched_barrier(0);
        __builtin_amdgcn_s_barrier();        // publish tile u to all waves
        __builtin_amdgcn_sched_barrier(0);

        const unsigned short* sbase = &lds[(u & 3) * 16384];
        frag_t af[8], bfv[4];
        #pragma unroll
        for (int m = 0; m < 8; ++m) {
            const int ra = wm + m * 16 + l16;
            af[m] = *(const frag_t*)&sbase[ra * 32 + ((quad ^ ((ra >> 1) & 3)) << 3)];
        }
        #pragma unroll
        for (int n = 0; n < 4; ++n) {
            const int rb = wn + n * 16 + l16;
            bfv[n] = *(const frag_t*)&sbase[8192 + rb * 32 + ((quad ^ ((rb >> 1) & 3)) << 3)];
        }
        __builtin_amdgcn_s_setprio(1);
        #pragma unroll
        for (int m = 0; m < 8; ++m)
            #pragma unroll
            for (int n = 0; n < 4; ++n)
                acc[m][n] = mfma_bf16(af[m], bfv[n], acc[m][n]);
        __builtin_amdgcn_s_setprio(0);
        __builtin_amdgcn_sched_barrier(0);
        __builtin_amdgcn_s_barrier();        // reads of slot[(u-1)&3] done
        __builtin_amdgcn_sched_barrier(0);
    }

    // C/D layout (verified m89/m91): col(n) = lane&15, row(m) = quad*4 + reg
    if (MODE == 1) {
        #pragma unroll
        for (int m = 0; m < 8; ++m) {
            const int gm = m0 + wm + m * 16 + quad * 4;
            #pragma unroll
            for (int n = 0; n < 4; ++n) {
                const int gn = n0 + wn + n * 16 + l16;
                #pragma unroll
                for (int v = 0; v < 4; ++v) {
                    float h = fmaxf(acc[m][n][v], 0.0f);  // fmax eats NaN pad rows too
                    Hout[(size_t)(gm + v) * LDO + gn] = f2bf(h * h);
                }
            }
        }
    } else {
        #pragma unroll
        for (int m = 0; m < 8; ++m) {
            const int gmb = m0 + wm + m * 16 + quad * 4;
            #pragma unroll
            for (int v = 0; v < 4; ++v) {
                const int gm = gmb + v;
                if (gm < cnt) {  // never read poisoned idx/mv beyond cnt
                    const int token = idx[gm];
                    const float scale = mv[gm];
                    #pragma unroll
                    for (int n = 0; n < 4; ++n) {
                        const int gn = n0 + wn + n * 16 + l16;
                        atomicAdd(&out[(size_t)token * LDO + gn], scale * acc[m][n][v]);
                    }
                }
            }
        }
    }
}

extern "C" void kernel_launch(void* const* d_in, const int* in_sizes, int n_in,
                              void* d_out, int out_size, void* d_ws, size_t ws_size,
                              hipStream_t stream)
{
    const float* x   = (const float*)d_in[0];
    const float* wfc = (const float*)d_in[1];
    const float* wpr = (const float*)d_in[2];
    const float* wrt = (const float*)d_in[3];
    float* out = (float*)d_out;

    // ws layout (bytes): [cnt 256][idx 32K][mv 32K][Xn 32M][Wfc 32M][Wpr 32M][H 128M]
    char* ws = (char*)d_ws;
    int*   cnt = (int*)ws;
    int*   idx = (int*)(ws + 256);
    float* mv  = (float*)(ws + 256 + 32768);
    unsigned short* Xn  = (unsigned short*)(ws + 65792);
    unsigned short* Wfc = (unsigned short*)(ws + 65792 + 33554432ULL);
    unsigned short* Wpr = (unsigned short*)(ws + 65792 + 67108864ULL);
    unsigned short* H   = (unsigned short*)(ws + 65792 + 100663296ULL);

    const int n4 = FDIM * CDIM / 4;  // float4 count per weight matrix
    zero_kernel<<<1, 64, 0, stream>>>(cnt);
    cvt2_kernel<<<(2 * n4 + 255) / 256, 256, 0, stream>>>(wfc, Wfc, n4, wpr, Wpr, n4);
    router_kernel<<<TOKENS, 256, 0, stream>>>(x, wrt, out, Xn, idx, mv, cnt);
    // GEMM1: H[m][f] = relu(Xn @ Wfc^T)^2, M=cnt (<=8192), N=8192, K=2048
    gemm_bt<CDIM, 1, FDIM, 1><<<dim3(32, FDIM / 256), 512, 131072, stream>>>(
        Xn, Wfc, H, nullptr, nullptr, nullptr, cnt);
    // GEMM2: out[token][c] += mask_i * (H @ Wpr^T), M=cnt, N=2048, K=8192, split-K x2
    gemm_bt<FDIM, 2, CDIM, 2><<<dim3(32, CDIM / 256, 2), 512, 131072, stream>>>(
        H, Wpr, nullptr, out, idx, mv, cnt);
}